// Round 3
// baseline (1612.850 us; speedup 1.0000x reference)
//
#include <hip/hip_runtime.h>

// GRNN scan: B=512 independent sequences, T=8192 steps.
// Round 2 (third attempt — rounds 1-2 died on broker/container infra, not
// the kernel; resubmitting unchanged to get a clean baseline measurement):
// monolithic correctness baseline. One thread per batch; full x + cov
// recurrence in registers. cov is recomputed redundantly per thread
// (it's batch-independent) — removing that redundancy is the next round.

#define DT_C 1e-3f
#define MAXU 0.1f
#define T_LEN 8192

__device__ __forceinline__ float clipf(float v, float lo, float hi) {
    return fminf(fmaxf(v, lo), hi);
}

__global__ __launch_bounds__(64) void grnn_mono(
    const float* __restrict__ inp,   // [B, T, 2]
    const float* __restrict__ Am,    // [2,2]
    const float* __restrict__ Cm,    // [2,2]
    const float* __restrict__ Dm,    // [2,2]
    float* __restrict__ out,         // [B, T, 2]
    int B)
{
    const int b = blockIdx.x * blockDim.x + threadIdx.x;
    if (b >= B) return;

    // 2x2 coefficient matrices (wave-uniform -> SGPRs)
    const float a00 = Am[0], a01 = Am[1], a10 = Am[2], a11 = Am[3];
    const float c00 = Cm[0], c01 = Cm[1], c10 = Cm[2], c11 = Cm[3];
    const float d00 = Dm[0], d01 = Dm[1], d10 = Dm[2], d11 = Dm[3];

    // state
    float x0 = 1.0f, x1 = 0.0f;
    float p00 = 1.0f, p01 = 0.0f, p10 = 0.0f, p11 = 1.0f;  // cov

    const float2* __restrict__ in2  = reinterpret_cast<const float2*>(inp) + (size_t)b * T_LEN;
    float2* __restrict__       out2 = reinterpret_cast<float2*>(out)       + (size_t)b * T_LEN;

#pragma unroll 4
    for (int t = 0; t < T_LEN; ++t) {
        // output uses pre-update state: out = (C x) * DT
        float2 o;
        o.x = (c00 * x0 + c01 * x1) * DT_C;
        o.y = (c10 * x0 + c11 * x1) * DT_C;
        out2[t] = o;

        // xicov = cov @ C^T + D^T   -> xi[i][j] = p[i][0]*C[j][0] + p[i][1]*C[j][1] + D[j][i]
        const float xi00 = p00 * c00 + p01 * c01 + d00;
        const float xi01 = p00 * c10 + p01 * c11 + d10;
        const float xi10 = p10 * c00 + p11 * c01 + d01;
        const float xi11 = p10 * c10 + p11 * c11 + d11;

        // M = A - xicov @ C
        const float m00 = a00 - (xi00 * c00 + xi01 * c10);
        const float m01 = a01 - (xi00 * c01 + xi01 * c11);
        const float m10 = a10 - (xi10 * c00 + xi11 * c10);
        const float m11 = a11 - (xi10 * c01 + xi11 * c11);

        const float2 dy = in2[t];

        // dx = (M x) * DT + xicov dy ; x += clip(dx, +-0.1)
        float dx0 = (m00 * x0 + m01 * x1) * DT_C + xi00 * dy.x + xi01 * dy.y;
        float dx1 = (m10 * x0 + m11 * x1) * DT_C + xi10 * dy.x + xi11 * dy.y;
        dx0 = clipf(dx0, -MAXU, MAXU);
        dx1 = clipf(dx1, -MAXU, MAXU);
        x0 += dx0;
        x1 += dx1;

        // G = A@cov + cov@A^T + D - xi@xi^T ; cov = clip(cov + G*DT, -1, 1)
        const float g00 = a00*p00 + a01*p10 + p00*a00 + p01*a01 + d00 - (xi00*xi00 + xi01*xi01);
        const float g01 = a00*p01 + a01*p11 + p00*a10 + p01*a11 + d01 - (xi00*xi10 + xi01*xi11);
        const float g10 = a10*p00 + a11*p10 + p10*a00 + p11*a01 + d10 - (xi10*xi00 + xi11*xi01);
        const float g11 = a10*p01 + a11*p11 + p10*a10 + p11*a11 + d11 - (xi10*xi10 + xi11*xi11);

        p00 = clipf(p00 + g00 * DT_C, -1.0f, 1.0f);
        p01 = clipf(p01 + g01 * DT_C, -1.0f, 1.0f);
        p10 = clipf(p10 + g10 * DT_C, -1.0f, 1.0f);
        p11 = clipf(p11 + g11 * DT_C, -1.0f, 1.0f);
    }
}

extern "C" void kernel_launch(void* const* d_in, const int* in_sizes, int n_in,
                              void* d_out, int out_size, void* d_ws, size_t ws_size,
                              hipStream_t stream) {
    const float* inp = (const float*)d_in[0];
    const float* Am  = (const float*)d_in[1];
    const float* Cm  = (const float*)d_in[2];
    const float* Dm  = (const float*)d_in[3];
    float* out = (float*)d_out;

    const int B = in_sizes[0] / (T_LEN * 2);  // 512
    // 8 blocks x 64 threads: each wave gets its own CU (round-robin across XCDs)
    hipLaunchKernelGGL(grnn_mono, dim3((B + 63) / 64), dim3(64), 0, stream,
                       inp, Am, Cm, Dm, out, B);
}